// Round 3
// baseline (375.687 us; speedup 1.0000x reference)
//
#include <hip/hip_runtime.h>

// Problem constants
#define EMB   1536
#define RANK  32
#define RANK2 1024   // RANK*RANK
#define N3    204
#define N10   34
#define D3    3840
#define D10   10240

#define ROWS3  (N3 * RANK2)    // 208896
#define ROWS10 (N10 * RANK2)   //  34816
#define GEMV_BLOCKS ((ROWS3 + ROWS10) / 4)   // 60928

#define SZ_LA3  ((size_t)N3  * RANK * D3)    // 25,067,520 floats
#define SZ_LA10 ((size_t)N10 * RANK * D10)   // 11,141,120 floats

// copy granularity: 4096 float4 per 256-thread block
#define CP_F4_PER_BLOCK 4096
#define CP3_BLOCKS  1530   // SZ_LA3/4/4096  (exact)
#define CP10_BLOCKS 680    // SZ_LA10/4/4096 (exact)

// pa: 4 consecutive columns per thread -> 1024 columns per 256-thread block
#define PA3_CHUNKS  4      // ceil(3840/1024)
#define PA10_CHUNKS 10     // 10240/1024 (exact)
#define PA3_BLOCKS  (N3 * PA3_CHUNKS)    // 816
#define PA10_BLOCKS (N10 * PA10_CHUNKS)  // 340

// ---------------------------------------------------------------------------
// Kernel 1: all GEMVs (one wave per row) + B3/B10 pass-through copies.
// ---------------------------------------------------------------------------
__device__ __forceinline__ void copy_block(const float4* __restrict__ src,
                                           float4* __restrict__ dst,
                                           int chunk) {
    const size_t base = (size_t)chunk * CP_F4_PER_BLOCK + threadIdx.x;
#pragma unroll
    for (int it = 0; it < CP_F4_PER_BLOCK / 256; ++it)   // 16 iterations
        dst[base + it * 256] = src[base + it * 256];
}

__global__ void k1_gemv_copy(const float* __restrict__ W3,
                             const float* __restrict__ b3,
                             const float* __restrict__ W10,
                             const float* __restrict__ b10,
                             const float* __restrict__ x,
                             float* __restrict__ P3,
                             float* __restrict__ P10,
                             const float4* __restrict__ B3,
                             float4* __restrict__ oB3,
                             const float4* __restrict__ B10,
                             float4* __restrict__ oB10) {
    int bid = blockIdx.x;
    if (bid < GEMV_BLOCKS) {
        const int wave = bid * 4 + (threadIdx.x >> 6);
        const int lane = threadIdx.x & 63;

        const float* W;
        const float* b;
        float* P;
        int row;
        if (wave < ROWS3) {
            W = W3; b = b3; P = P3; row = wave;
        } else {
            W = W10; b = b10; P = P10; row = wave - ROWS3;
        }

        const float* w = W + (size_t)row * EMB;
        float acc = 0.f;
#pragma unroll
        for (int it = 0; it < EMB / 256; ++it) {      // 6 iterations
            const int e = (it * 64 + lane) * 4;
            const float4 wv = *reinterpret_cast<const float4*>(w + e);
            const float4 xv = *reinterpret_cast<const float4*>(x + e);
            acc = fmaf(wv.x, xv.x, acc);
            acc = fmaf(wv.y, xv.y, acc);
            acc = fmaf(wv.z, xv.z, acc);
            acc = fmaf(wv.w, xv.w, acc);
        }
#pragma unroll
        for (int off = 32; off > 0; off >>= 1)
            acc += __shfl_down(acc, off);
        if (lane == 0) P[row] = acc + b[row];
        return;
    }
    bid -= GEMV_BLOCKS;
    if (bid < CP3_BLOCKS) { copy_block(B3, oB3, bid); return; }
    copy_block(B10, oB10, bid - CP3_BLOCKS);
}

// ---------------------------------------------------------------------------
// Kernel 2: la[i, d0:d0+4] = sum_j P[i,j] * A[j, d0:d0+4], 4 cols per thread.
// Ps rows read as float4 LDS broadcasts (wave-uniform, conflict-free);
// A loads / la stores are float4, fully coalesced across the block.
// Summation order over j identical to prior rounds (bitwise-same results).
// ---------------------------------------------------------------------------
__global__ __launch_bounds__(256) void k2_pa(const float* __restrict__ P3,
                                             const float* __restrict__ A3,
                                             float* __restrict__ la3,
                                             const float* __restrict__ P10,
                                             const float* __restrict__ A10,
                                             float* __restrict__ la10) {
    int bid = blockIdx.x;
    const float* P; const float* A; float* la; int D, m, chunk;
    if (bid < PA3_BLOCKS) {
        m = bid >> 2; chunk = bid & 3;
        P = P3; A = A3; la = la3; D = D3;
    } else {
        bid -= PA3_BLOCKS;
        m = bid / PA10_CHUNKS; chunk = bid % PA10_CHUNKS;
        P = P10; A = A10; la = la10; D = D10;
    }

    __shared__ float Ps[RANK2];
    const float4* Pm4 = reinterpret_cast<const float4*>(P + (size_t)m * RANK2);
    reinterpret_cast<float4*>(Ps)[threadIdx.x] = Pm4[threadIdx.x];  // 256 f4 = 1024 floats
    __syncthreads();

    const int d0 = chunk * 1024 + (int)threadIdx.x * 4;
    if (d0 >= D) return;   // only in the last module3 chunk

    const float* a = A + (size_t)m * RANK * D + d0;
    float4 av[RANK];
#pragma unroll
    for (int j = 0; j < RANK; ++j)
        av[j] = *reinterpret_cast<const float4*>(a + (size_t)j * D);

    const float4* Ps4 = reinterpret_cast<const float4*>(Ps);
    float* o = la + (size_t)m * RANK * D + d0;
#pragma unroll
    for (int i = 0; i < RANK; ++i) {
        float4 pr[8];
#pragma unroll
        for (int j8 = 0; j8 < 8; ++j8)
            pr[j8] = Ps4[i * 8 + j8];    // wave-uniform b128 broadcast
        float4 acc = make_float4(0.f, 0.f, 0.f, 0.f);
#pragma unroll
        for (int j8 = 0; j8 < 8; ++j8) {
            const float4 p4 = pr[j8];
            const float4 a0 = av[j8 * 4 + 0];
            const float4 a1 = av[j8 * 4 + 1];
            const float4 a2 = av[j8 * 4 + 2];
            const float4 a3 = av[j8 * 4 + 3];
            acc.x = fmaf(p4.x, a0.x, acc.x); acc.y = fmaf(p4.x, a0.y, acc.y);
            acc.z = fmaf(p4.x, a0.z, acc.z); acc.w = fmaf(p4.x, a0.w, acc.w);
            acc.x = fmaf(p4.y, a1.x, acc.x); acc.y = fmaf(p4.y, a1.y, acc.y);
            acc.z = fmaf(p4.y, a1.z, acc.z); acc.w = fmaf(p4.y, a1.w, acc.w);
            acc.x = fmaf(p4.z, a2.x, acc.x); acc.y = fmaf(p4.z, a2.y, acc.y);
            acc.z = fmaf(p4.z, a2.z, acc.z); acc.w = fmaf(p4.z, a2.w, acc.w);
            acc.x = fmaf(p4.w, a3.x, acc.x); acc.y = fmaf(p4.w, a3.y, acc.y);
            acc.z = fmaf(p4.w, a3.z, acc.z); acc.w = fmaf(p4.w, a3.w, acc.w);
        }
        *reinterpret_cast<float4*>(o + (size_t)i * D) = acc;
    }
}

// ---------------------------------------------------------------------------
// Launch
// Inputs (setup_inputs order): x, Wp3, bp3, Wp10, bp10, A3, A10, B3, B10
// Output layout (flat concat): la3 | la10 | B3 | B10
// ---------------------------------------------------------------------------
extern "C" void kernel_launch(void* const* d_in, const int* in_sizes, int n_in,
                              void* d_out, int out_size, void* d_ws, size_t ws_size,
                              hipStream_t stream) {
    const float* x    = (const float*)d_in[0];
    const float* Wp3  = (const float*)d_in[1];
    const float* bp3  = (const float*)d_in[2];
    const float* Wp10 = (const float*)d_in[3];
    const float* bp10 = (const float*)d_in[4];
    const float* A3   = (const float*)d_in[5];
    const float* A10  = (const float*)d_in[6];
    const float* B3   = (const float*)d_in[7];
    const float* B10  = (const float*)d_in[8];

    float* out = (float*)d_out;

    // workspace: P3 (204*1024 f32) then P10 (34*1024 f32)
    float* P3  = (float*)d_ws;
    float* P10 = P3 + (size_t)N3 * RANK2;

    float* la3  = out;
    float* la10 = out + SZ_LA3;
    float* oB3  = la10 + SZ_LA10;
    float* oB10 = oB3 + SZ_LA3;

    // K1: all GEMVs + B copies (independent work fused into one launch)
    const int k1_blocks = GEMV_BLOCKS + CP3_BLOCKS + CP10_BLOCKS;
    k1_gemv_copy<<<k1_blocks, 256, 0, stream>>>(
        Wp3, bp3, Wp10, bp10, x, P3, P10,
        (const float4*)B3, (float4*)oB3,
        (const float4*)B10, (float4*)oB10);

    // K2: pa (the only gemv-dependent phase), register-tiled 4 cols/thread
    k2_pa<<<PA3_BLOCKS + PA10_BLOCKS, 256, 0, stream>>>(
        P3, A3, la3, P10, A10, la10);
}

// Round 4
// 375.174 us; speedup vs baseline: 1.0014x; 1.0014x over previous
//
#include <hip/hip_runtime.h>

// Problem constants
#define EMB   1536
#define RANK  32
#define RANK2 1024   // RANK*RANK
#define N3    204
#define N10   34
#define D3    3840
#define D10   10240

#define ROWS3    (N3 * RANK2)      // 208896
#define ROWS10   (N10 * RANK2)     //  34816
#define ROWS_ALL (ROWS3 + ROWS10)  // 243712

// gemv: 8 rows per wave, 4 waves/block -> 32 rows/block
#define RPW 8
#define GEMV_BLOCKS (ROWS_ALL / (4 * RPW))   // 7616

#define SZ_LA3  ((size_t)N3  * RANK * D3)    // 25,067,520 floats
#define SZ_LA10 ((size_t)N10 * RANK * D10)   // 11,141,120 floats

// copies: 8192 float4 (128 KB r+w) per 256-thread block
#define CP_F4 8192
#define CP3_BLOCKS  765    // SZ_LA3/4/8192  (exact)
#define CP10_BLOCKS 340    // SZ_LA10/4/8192 (exact)

// pa: 4 consecutive columns per thread -> 1024 columns per block
#define PA3_CHUNKS  4
#define PA10_CHUNKS 10
#define PA3_BLOCKS  (N3 * PA3_CHUNKS)    // 816
#define PA10_BLOCKS (N10 * PA10_CHUNKS)  // 340
#define PA_BLOCKS   (PA3_BLOCKS + PA10_BLOCKS)  // 1156

// ---------------------------------------------------------------------------
// K1: all GEMVs. One wave handles 8 consecutive rows (48 KB streamed);
// x held in 24 VGPRs for the wave's lifetime; P written as 2x float4.
// ---------------------------------------------------------------------------
__global__ __launch_bounds__(256) void k1_gemv(
    const float* __restrict__ W3, const float* __restrict__ b3,
    const float* __restrict__ W10, const float* __restrict__ b10,
    const float* __restrict__ x,
    float* __restrict__ P3, float* __restrict__ P10)
{
    const int wave = blockIdx.x * 4 + (threadIdx.x >> 6);
    const int lane = threadIdx.x & 63;
    int r0 = wave * RPW;

    const float* W; const float* b; float* P;
    if (r0 < ROWS3) { W = W3; b = b3; P = P3; }
    else            { W = W10; b = b10; P = P10; r0 -= ROWS3; }

    // x staged in registers, reused across all 8 rows
    float4 xv[6];
#pragma unroll
    for (int it = 0; it < 6; ++it)
        xv[it] = *reinterpret_cast<const float4*>(x + it * 256 + lane * 4);

    const float* w = W + (size_t)r0 * EMB;
    float acc[RPW];
#pragma unroll
    for (int rr = 0; rr < RPW; ++rr) {
        float a = 0.f;
#pragma unroll
        for (int it = 0; it < 6; ++it) {
            const float4 wv = *reinterpret_cast<const float4*>(
                w + (size_t)rr * EMB + it * 256 + lane * 4);
            a = fmaf(wv.x, xv[it].x, a);
            a = fmaf(wv.y, xv[it].y, a);
            a = fmaf(wv.z, xv[it].z, a);
            a = fmaf(wv.w, xv[it].w, a);
        }
        acc[rr] = a;
    }
#pragma unroll
    for (int rr = 0; rr < RPW; ++rr) {
#pragma unroll
        for (int off = 32; off > 0; off >>= 1)
            acc[rr] += __shfl_down(acc[rr], off);
    }
    if (lane == 0) {
        const float4 bv0 = *reinterpret_cast<const float4*>(b + r0);
        const float4 bv1 = *reinterpret_cast<const float4*>(b + r0 + 4);
        float4 o0 = make_float4(acc[0] + bv0.x, acc[1] + bv0.y,
                                acc[2] + bv0.z, acc[3] + bv0.w);
        float4 o1 = make_float4(acc[4] + bv1.x, acc[5] + bv1.y,
                                acc[6] + bv1.z, acc[7] + bv1.w);
        *reinterpret_cast<float4*>(P + r0)     = o0;
        *reinterpret_cast<float4*>(P + r0 + 4) = o1;
    }
}

// ---------------------------------------------------------------------------
// K2: pa (register-tiled, 4 cols/thread) + B pass-through copies.
// ---------------------------------------------------------------------------
__device__ __forceinline__ void copy_block(const float4* __restrict__ src,
                                           float4* __restrict__ dst,
                                           int chunk) {
    const size_t base = (size_t)chunk * CP_F4 + threadIdx.x;
#pragma unroll
    for (int it = 0; it < CP_F4 / 256; ++it)   // 32 iterations
        dst[base + it * 256] = src[base + it * 256];
}

__global__ __launch_bounds__(256) void k2_pa_copy(
    const float* __restrict__ P3, const float* __restrict__ A3,
    float* __restrict__ la3,
    const float* __restrict__ P10, const float* __restrict__ A10,
    float* __restrict__ la10,
    const float4* __restrict__ B3,  float4* __restrict__ oB3,
    const float4* __restrict__ B10, float4* __restrict__ oB10)
{
    int bid = blockIdx.x;
    if (bid >= PA_BLOCKS) {
        bid -= PA_BLOCKS;
        if (bid < CP3_BLOCKS) { copy_block(B3, oB3, bid); return; }
        copy_block(B10, oB10, bid - CP3_BLOCKS);
        return;
    }

    const float* P; const float* A; float* la; int D, m, chunk;
    if (bid < PA3_BLOCKS) {
        m = bid >> 2; chunk = bid & 3;
        P = P3; A = A3; la = la3; D = D3;
    } else {
        bid -= PA3_BLOCKS;
        m = bid / PA10_CHUNKS; chunk = bid % PA10_CHUNKS;
        P = P10; A = A10; la = la10; D = D10;
    }

    __shared__ float Ps[RANK2];
    const float4* Pm4 = reinterpret_cast<const float4*>(P + (size_t)m * RANK2);
    reinterpret_cast<float4*>(Ps)[threadIdx.x] = Pm4[threadIdx.x];
    __syncthreads();

    const int d0 = chunk * 1024 + (int)threadIdx.x * 4;
    if (d0 >= D) return;   // only in last module-3 chunk

    const float* a = A + (size_t)m * RANK * D + d0;
    float4 av[RANK];
#pragma unroll
    for (int j = 0; j < RANK; ++j)
        av[j] = *reinterpret_cast<const float4*>(a + (size_t)j * D);

    const float4* Ps4 = reinterpret_cast<const float4*>(Ps);
    float* o = la + (size_t)m * RANK * D + d0;
#pragma unroll
    for (int i = 0; i < RANK; ++i) {
        float4 pr[8];
#pragma unroll
        for (int j8 = 0; j8 < 8; ++j8)
            pr[j8] = Ps4[i * 8 + j8];    // wave-uniform b128 broadcast
        float4 acc = make_float4(0.f, 0.f, 0.f, 0.f);
#pragma unroll
        for (int j8 = 0; j8 < 8; ++j8) {
            const float4 p4 = pr[j8];
            const float4 a0 = av[j8 * 4 + 0];
            const float4 a1 = av[j8 * 4 + 1];
            const float4 a2 = av[j8 * 4 + 2];
            const float4 a3 = av[j8 * 4 + 3];
            acc.x = fmaf(p4.x, a0.x, acc.x); acc.y = fmaf(p4.x, a0.y, acc.y);
            acc.z = fmaf(p4.x, a0.z, acc.z); acc.w = fmaf(p4.x, a0.w, acc.w);
            acc.x = fmaf(p4.y, a1.x, acc.x); acc.y = fmaf(p4.y, a1.y, acc.y);
            acc.z = fmaf(p4.y, a1.z, acc.z); acc.w = fmaf(p4.y, a1.w, acc.w);
            acc.x = fmaf(p4.z, a2.x, acc.x); acc.y = fmaf(p4.z, a2.y, acc.y);
            acc.z = fmaf(p4.z, a2.z, acc.z); acc.w = fmaf(p4.z, a2.w, acc.w);
            acc.x = fmaf(p4.w, a3.x, acc.x); acc.y = fmaf(p4.w, a3.y, acc.y);
            acc.z = fmaf(p4.w, a3.z, acc.z); acc.w = fmaf(p4.w, a3.w, acc.w);
        }
        *reinterpret_cast<float4*>(o + (size_t)i * D) = acc;
    }
}

// ---------------------------------------------------------------------------
// Launch
// Inputs (setup_inputs order): x, Wp3, bp3, Wp10, bp10, A3, A10, B3, B10
// Output layout (flat concat): la3 | la10 | B3 | B10
// ---------------------------------------------------------------------------
extern "C" void kernel_launch(void* const* d_in, const int* in_sizes, int n_in,
                              void* d_out, int out_size, void* d_ws, size_t ws_size,
                              hipStream_t stream) {
    const float* x    = (const float*)d_in[0];
    const float* Wp3  = (const float*)d_in[1];
    const float* bp3  = (const float*)d_in[2];
    const float* Wp10 = (const float*)d_in[3];
    const float* bp10 = (const float*)d_in[4];
    const float* A3   = (const float*)d_in[5];
    const float* A10  = (const float*)d_in[6];
    const float* B3   = (const float*)d_in[7];
    const float* B10  = (const float*)d_in[8];

    float* out = (float*)d_out;

    // workspace: P3 then P10
    float* P3  = (float*)d_ws;
    float* P10 = P3 + (size_t)N3 * RANK2;

    float* la3  = out;
    float* la10 = out + SZ_LA3;
    float* oB3  = la10 + SZ_LA10;
    float* oB10 = oB3 + SZ_LA3;

    // K1: all GEMVs, fat blocks (32 rows / 192 KB traffic per block)
    k1_gemv<<<GEMV_BLOCKS, 256, 0, stream>>>(Wp3, bp3, Wp10, bp10, x, P3, P10);

    // K2: pa + B copies
    k2_pa_copy<<<PA_BLOCKS + CP3_BLOCKS + CP10_BLOCKS, 256, 0, stream>>>(
        P3, A3, la3, P10, A10, la10,
        (const float4*)B3, (float4*)oB3,
        (const float4*)B10, (float4*)oB10);
}

// Round 6
// 327.786 us; speedup vs baseline: 1.1461x; 1.1446x over previous
//
#include <hip/hip_runtime.h>

// Problem constants
#define EMB   1536
#define RANK  32
#define RANK2 1024   // RANK*RANK
#define N3    204
#define N10   34
#define D3    3840
#define D10   10240

#define ROWS3    (N3 * RANK2)      // 208896
#define ROWS10   (N10 * RANK2)     //  34816
#define ROWS_ALL (ROWS3 + ROWS10)  // 243712
#define GEMV_BLOCKS (ROWS_ALL / 4) // 60928  (1 row per wave, 4 waves/block)

#define SZ_LA3  ((size_t)N3  * RANK * D3)    // 25,067,520 floats
#define SZ_LA10 ((size_t)N10 * RANK * D10)   // 11,141,120 floats

// K2 pa blocks: 4 cols/thread, 1024 cols per 256-thread block
#define PA3_CHUNKS  4
#define PA10_CHUNKS 10
#define PA3_BLOCKS  (N3 * PA3_CHUNKS)    // 816
#define PA10_BLOCKS (N10 * PA10_CHUNKS)  // 340
#define NP_BLOCKS   (PA3_BLOCKS + PA10_BLOCKS)  // 1156

// K2 copy blocks: 4096 float4 (64 KB r + 64 KB w) per block
#define CP_F4 4096
#define CP3_BLOCKS  1530   // SZ_LA3/4/4096  (exact)
#define CP10_BLOCKS 680    // SZ_LA10/4/4096 (exact)
#define NC_BLOCKS   (CP3_BLOCKS + CP10_BLOCKS)  // 2210
#define NT_BLOCKS   (NP_BLOCKS + NC_BLOCKS)     // 3366

// Native clang vector type — __builtin_nontemporal_* accepts these
typedef float float4v __attribute__((ext_vector_type(4)));

__device__ __forceinline__ float4v nt_load4(const float* p) {
    return __builtin_nontemporal_load(reinterpret_cast<const float4v*>(p));
}
__device__ __forceinline__ void nt_store4(float* p, float4v v) {
    __builtin_nontemporal_store(v, reinterpret_cast<float4v*>(p));
}

// ---------------------------------------------------------------------------
// K1: all GEMVs. One wave per row:  P[row] = dot(W[row,:], x) + b[row].
// W is a 1.5 GB single-use stream -> nt loads. x (6 KB) stays cached.
// ---------------------------------------------------------------------------
__global__ __launch_bounds__(256) void k1_gemv(
    const float* __restrict__ W3, const float* __restrict__ b3,
    const float* __restrict__ W10, const float* __restrict__ b10,
    const float* __restrict__ x,
    float* __restrict__ P3, float* __restrict__ P10)
{
    const int wave = blockIdx.x * 4 + (threadIdx.x >> 6);
    const int lane = threadIdx.x & 63;

    const float* W; const float* b; float* P; int row;
    if (wave < ROWS3) { W = W3; b = b3; P = P3; row = wave; }
    else              { W = W10; b = b10; P = P10; row = wave - ROWS3; }

    const float* w = W + (size_t)row * EMB;
    float acc = 0.f;
#pragma unroll
    for (int it = 0; it < EMB / 256; ++it) {      // 6 iterations
        const int e = (it * 64 + lane) * 4;
        const float4v wv = nt_load4(w + e);
        const float4 xv = *reinterpret_cast<const float4*>(x + e);
        acc = fmaf(wv.x, xv.x, acc);
        acc = fmaf(wv.y, xv.y, acc);
        acc = fmaf(wv.z, xv.z, acc);
        acc = fmaf(wv.w, xv.w, acc);
    }
#pragma unroll
    for (int off = 32; off > 0; off >>= 1)
        acc += __shfl_down(acc, off);
    if (lane == 0) P[row] = acc + b[row];
}

// ---------------------------------------------------------------------------
// K2: pa (reg-tiled, 4 cols/thread) + B copies, Bresenham-interleaved so the
// copy traffic is spread evenly across the grid (no end-of-grid copy clump).
// ---------------------------------------------------------------------------
__device__ __forceinline__ void copy_block(const float* __restrict__ src,
                                           float* __restrict__ dst,
                                           int chunk) {
    const size_t base = ((size_t)chunk * CP_F4 + threadIdx.x) * 4;
#pragma unroll
    for (int it = 0; it < CP_F4 / 256; ++it)   // 16 iterations
        nt_store4(dst + base + (size_t)it * 1024, nt_load4(src + base + (size_t)it * 1024));
}

__device__ __forceinline__ void pa_block(const float* __restrict__ P,
                                         const float* __restrict__ A,
                                         float* __restrict__ la,
                                         int m, int chunk, int D) {
    __shared__ float Ps[RANK2];
    const float4* Pm4 = reinterpret_cast<const float4*>(P + (size_t)m * RANK2);
    reinterpret_cast<float4*>(Ps)[threadIdx.x] = Pm4[threadIdx.x];
    __syncthreads();

    const int d0 = chunk * 1024 + (int)threadIdx.x * 4;
    if (d0 >= D) return;   // only in last module-3 chunk (after the sync)

    const float* a = A + (size_t)m * RANK * D + d0;
    float4v av[RANK];
#pragma unroll
    for (int j = 0; j < RANK; ++j)
        av[j] = nt_load4(a + (size_t)j * D);

    const float4* Ps4 = reinterpret_cast<const float4*>(Ps);
    float* o = la + (size_t)m * RANK * D + d0;
#pragma unroll
    for (int i = 0; i < RANK; ++i) {
        float4 pr[8];
#pragma unroll
        for (int j8 = 0; j8 < 8; ++j8)
            pr[j8] = Ps4[i * 8 + j8];    // wave-uniform b128 broadcast
        float4v acc = (float4v)(0.f);
#pragma unroll
        for (int j8 = 0; j8 < 8; ++j8) {
            const float4 p4 = pr[j8];
            const float4v a0 = av[j8 * 4 + 0];
            const float4v a1 = av[j8 * 4 + 1];
            const float4v a2 = av[j8 * 4 + 2];
            const float4v a3 = av[j8 * 4 + 3];
            acc.x = fmaf(p4.x, a0.x, acc.x); acc.y = fmaf(p4.x, a0.y, acc.y);
            acc.z = fmaf(p4.x, a0.z, acc.z); acc.w = fmaf(p4.x, a0.w, acc.w);
            acc.x = fmaf(p4.y, a1.x, acc.x); acc.y = fmaf(p4.y, a1.y, acc.y);
            acc.z = fmaf(p4.y, a1.z, acc.z); acc.w = fmaf(p4.y, a1.w, acc.w);
            acc.x = fmaf(p4.z, a2.x, acc.x); acc.y = fmaf(p4.z, a2.y, acc.y);
            acc.z = fmaf(p4.z, a2.z, acc.z); acc.w = fmaf(p4.z, a2.w, acc.w);
            acc.x = fmaf(p4.w, a3.x, acc.x); acc.y = fmaf(p4.w, a3.y, acc.y);
            acc.z = fmaf(p4.w, a3.z, acc.z); acc.w = fmaf(p4.w, a3.w, acc.w);
        }
        nt_store4(o + (size_t)i * D, acc);
    }
}

__global__ __launch_bounds__(256) void k2_pa_copy(
    const float* __restrict__ P3, const float* __restrict__ A3,
    float* __restrict__ la3,
    const float* __restrict__ P10, const float* __restrict__ A10,
    float* __restrict__ la10,
    const float* __restrict__ B3,  float* __restrict__ oB3,
    const float* __restrict__ B10, float* __restrict__ oB10)
{
    const int k = blockIdx.x;
    // Bresenham spread: pa blocks evenly distributed among copy blocks.
    const int b0 = (int)(((long long)k       * NP_BLOCKS) / NT_BLOCKS);
    const int b1 = (int)(((long long)(k + 1) * NP_BLOCKS) / NT_BLOCKS);
    if (b1 > b0) {
        // pa block index b0
        int idx = b0;
        if (idx < PA3_BLOCKS) {
            pa_block(P3, A3, la3, idx >> 2, idx & 3, D3);
        } else {
            idx -= PA3_BLOCKS;
            pa_block(P10, A10, la10, idx / PA10_CHUNKS, idx % PA10_CHUNKS, D10);
        }
    } else {
        // copy block index k - b0
        int idx = k - b0;
        if (idx < CP3_BLOCKS) copy_block(B3, oB3, idx);
        else                  copy_block(B10, oB10, idx - CP3_BLOCKS);
    }
}

// ---------------------------------------------------------------------------
// Launch
// Inputs (setup_inputs order): x, Wp3, bp3, Wp10, bp10, A3, A10, B3, B10
// Output layout (flat concat): la3 | la10 | B3 | B10
// ---------------------------------------------------------------------------
extern "C" void kernel_launch(void* const* d_in, const int* in_sizes, int n_in,
                              void* d_out, int out_size, void* d_ws, size_t ws_size,
                              hipStream_t stream) {
    const float* x    = (const float*)d_in[0];
    const float* Wp3  = (const float*)d_in[1];
    const float* bp3  = (const float*)d_in[2];
    const float* Wp10 = (const float*)d_in[3];
    const float* bp10 = (const float*)d_in[4];
    const float* A3   = (const float*)d_in[5];
    const float* A10  = (const float*)d_in[6];
    const float* B3   = (const float*)d_in[7];
    const float* B10  = (const float*)d_in[8];

    float* out = (float*)d_out;

    // workspace: P3 then P10
    float* P3  = (float*)d_ws;
    float* P10 = P3 + (size_t)N3 * RANK2;

    float* la3  = out;
    float* la10 = out + SZ_LA3;
    float* oB3  = la10 + SZ_LA10;
    float* oB10 = oB3 + SZ_LA3;

    // K1: all GEMVs (1 row/wave, nt W stream)
    k1_gemv<<<GEMV_BLOCKS, 256, 0, stream>>>(Wp3, bp3, Wp10, bp10, x, P3, P10);

    // K2: pa + B copies, interleaved
    k2_pa_copy<<<NT_BLOCKS, 256, 0, stream>>>(
        P3, A3, la3, P10, A10, la10,
        B3, oB3, B10, oB10);
}